// Round 8
// baseline (737.486 us; speedup 1.0000x reference)
//
#include <hip/hip_runtime.h>
#include <math.h>
#include <float.h>

#define N_FR 32768
#define M_DIM 1024
#define D_DIM 512
#define K_CB 4096

// ---- d_out layout (floats) ----
static const long long OUT_ELEMS = (long long)N_FR * M_DIM;
static const long long LOSS_OFF  = OUT_ELEMS;
static const long long ENC_OFF   = OUT_ELEMS + 2;
static const long long Z_OFF   = ENC_OFF + 2;                           // fp32 z [N][D]
static const long long DC_OFF  = Z_OFF  + (long long)N_FR * D_DIM;      // fp32 dec_cb [K][M]
static const long long XH_OFF  = DC_OFF + (long long)K_CB * M_DIM;
static const long long XL_OFF  = XH_OFF + (long long)N_FR * M_DIM / 2;
static const long long WH_OFF  = XL_OFF + (long long)N_FR * M_DIM / 2;  // enc_w hi only
static const long long CH_OFF  = WH_OFF + (long long)D_DIM * M_DIM / 2; // cb hi only
static const long long ZH_OFF  = CH_OFF + (long long)K_CB * D_DIM / 2;  // z hi only
static const long long PV_OFF  = ZH_OFF + (long long)N_FR * D_DIM / 2;  // partial best val [4][N]
static const long long PI_OFF  = PV_OFF + 4LL * N_FR;                   // partial best idx [4][N]
static const long long DWH_OFF = PI_OFF + 4LL * N_FR;                   // dec_w hi
static const long long DWL_OFF = DWH_OFF + (long long)M_DIM * D_DIM / 2;// dec_w lo
static const long long SNP_OFF = DWL_OFF + (long long)M_DIM * D_DIM / 2;// ||z||^2 partials [16][N]
static const long long LP_OFF  = SNP_OFF + 16LL * N_FR;                 // loss partials [128]

typedef __attribute__((ext_vector_type(8))) short bf16x8;
typedef __attribute__((ext_vector_type(8))) unsigned short u16x8;
typedef __attribute__((ext_vector_type(4))) float f32x4;

__device__ __forceinline__ unsigned short f2bf(float f) {
    unsigned u = __float_as_uint(f);
    return (unsigned short)((u + 0x7fffu + ((u >> 16) & 1u)) >> 16);
}
__device__ __forceinline__ float bf2f(unsigned short h) {
    return __uint_as_float(((unsigned)h) << 16);
}
__device__ __forceinline__ void gl_lds16(const void* g, void* l) {
    __builtin_amdgcn_global_load_lds(
        (const __attribute__((address_space(1))) unsigned int*)g,
        (__attribute__((address_space(3))) unsigned int*)l,
        16, 0, 0);
}

// ------------------------------------------------------------------
// fp32 [R][C] -> packed bf16 hi (+ optional lo), fragment-blocked:
// shorts[b*512 + lane*8 + j], b = (r>>4)*(C/32) + (c>>5),
// lane = (r&15) + 16*((c>>3)&3), j = c&7.
// ------------------------------------------------------------------
__device__ __forceinline__ void conv_body(const float* in, unsigned short* hi,
                                          unsigned short* lo, int C, int KC, int w)
{
    int lane = threadIdx.x & 63;
    int bn = w / KC, ck = w % KC;
    int r = bn * 16 + (lane & 15);
    int c = ck * 32 + (lane >> 4) * 8;
    const float4* p = (const float4*)&in[(size_t)r * C + c];
    float4 v0 = p[0], v1 = p[1];
    float f[8] = {v0.x, v0.y, v0.z, v0.w, v1.x, v1.y, v1.z, v1.w};
    u16x8 hv, lv;
    #pragma unroll
    for (int j = 0; j < 8; ++j) {
        unsigned short h = f2bf(f[j]);
        hv[j] = h;
        lv[j] = f2bf(f[j] - bf2f(h));
    }
    size_t o = (size_t)w * 512 + lane * 8;
    *(u16x8*)&hi[o] = hv;
    if (lo) *(u16x8*)&lo[o] = lv;
}

__global__ __launch_bounds__(256)
void conv_all(const float* __restrict__ x,  const float* __restrict__ ew,
              const float* __restrict__ cb, const float* __restrict__ dw,
              unsigned short* __restrict__ xh,  unsigned short* __restrict__ xl,
              unsigned short* __restrict__ wh,
              unsigned short* __restrict__ ch,
              unsigned short* __restrict__ dwh, unsigned short* __restrict__ dwl)
{
    int b = blockIdx.x;
    const float* in; unsigned short* hi; unsigned short* lo; int C; int w0;
    if (b < 16384)      { in = x;  hi = xh;  lo = xl;      C = 1024; w0 = b; }
    else if (b < 16640) { in = ew; hi = wh;  lo = nullptr; C = 1024; w0 = b - 16384; }
    else if (b < 17664) { in = cb; hi = ch;  lo = nullptr; C = 512;  w0 = b - 16640; }
    else                { in = dw; hi = dwh; lo = dwl;     C = 512;  w0 = b - 17664; }
    int KC = C / 32;
    conv_body(in, hi, lo, C, KC, w0 * 4 + (threadIdx.x >> 6));
}

// ------------------------------------------------------------------
// z -> packed zh (hi only) + per-chunk row-norm partials snp[ck][row].
// ------------------------------------------------------------------
__global__ __launch_bounds__(256)
void conv_z(const float* __restrict__ z, unsigned short* __restrict__ zh,
            float* __restrict__ snp)
{
    int w = blockIdx.x * 4 + (threadIdx.x >> 6);
    int lane = threadIdx.x & 63;
    int bn = w >> 4, ck = w & 15;
    int r = bn * 16 + (lane & 15);
    int c = ck * 32 + (lane >> 4) * 8;
    const float4* p = (const float4*)&z[(size_t)r * D_DIM + c];
    float4 v0 = p[0], v1 = p[1];
    float f[8] = {v0.x, v0.y, v0.z, v0.w, v1.x, v1.y, v1.z, v1.w};
    u16x8 hv;
    float s = 0.f;
    #pragma unroll
    for (int j = 0; j < 8; ++j) {
        hv[j] = f2bf(f[j]);
        s = fmaf(f[j], f[j], s);
    }
    *(u16x8*)&zh[(size_t)w * 512 + lane * 8] = hv;
    s += __shfl_xor(s, 16);
    s += __shfl_xor(s, 32);
    if ((lane >> 4) == 0) snp[(size_t)ck * N_FR + r] = s;
}

// ------------------------------------------------------------------
// 2-pass packed bf16 MFMA GEMM, double-buffered with counted vmcnt:
// per step {stage(t+1); vmcnt(6); bar; ds_read; lgkm(0); bar; MFMA}.
// MODE 0 (encoder): A split (s0=Ah, s1=Al, s2=Bh), BN epilogue.
// MODE 1 (decoder): B split (s0=Ah, s1=Bh, s2=Bl), bias epilogue.
// ------------------------------------------------------------------
template<int MODE>
__global__ __launch_bounds__(256, 2)
void gemm2(const unsigned short* __restrict__ s0_, const unsigned short* __restrict__ s1_,
           const unsigned short* __restrict__ s2_,
           const float* __restrict__ bias, const float* __restrict__ gamma,
           const float* __restrict__ beta, const float* __restrict__ mean,
           const float* __restrict__ var, float* __restrict__ C,
           int nbi, int nkb, int NJ)
{
    __shared__ unsigned short lds[24576];   // 2 bufs x 12288 shorts
    const int tid = threadIdx.x, wid = tid >> 6, lane = tid & 63;
    const int wr = wid >> 1, wc = wid & 1;
    const int bi = blockIdx.x % nbi, bj = blockIdx.x / nbi;

    auto stage = [&](int ks, int bufsel) {
        unsigned short* dst = lds + bufsel * 12288;
        #pragma unroll
        for (int q = 0; q < 6; ++q) {
            int id = wid * 6 + q;
            int arr = id >> 3, rb = id & 7;
            const unsigned short* base = arr == 0 ? s0_ : arr == 1 ? s1_ : s2_;
            int bsel = (arr == 0) ? bi : (arr == 1 ? (MODE == 0 ? bi : bj) : bj);
            size_t b = (size_t)(bsel * 8 + rb) * nkb + ks;
            gl_lds16(base + b * 512 + lane * 8, dst + id * 512);
        }
    };

    f32x4 acc[4][4];
    #pragma unroll
    for (int i = 0; i < 4; ++i)
        #pragma unroll
        for (int j = 0; j < 4; ++j) acc[i][j] = (f32x4){0.f, 0.f, 0.f, 0.f};

    stage(0, 0);
    asm volatile("s_waitcnt vmcnt(0)");
    __builtin_amdgcn_s_barrier();

    for (int ks = 0; ks < nkb; ++ks) {
        int cur = ks & 1;
        if (ks + 1 < nkb) {
            stage(ks + 1, cur ^ 1);
            asm volatile("s_waitcnt vmcnt(6)");   // prev stage complete (6 newest in flight)
        } else {
            asm volatile("s_waitcnt vmcnt(0)");
        }
        __builtin_amdgcn_s_barrier();             // publish stage(ks) across waves

        const unsigned short* L = lds + cur * 12288;
        bf16x8 r0[4], r1[4], r2[4];
        #pragma unroll
        for (int i = 0; i < 4; ++i) {
            r0[i] = *(const bf16x8*)(L + (wr * 4 + i) * 512 + lane * 8);
            r1[i] = *(const bf16x8*)(L + 4096 + ((MODE == 0 ? wr : wc) * 4 + i) * 512 + lane * 8);
            r2[i] = *(const bf16x8*)(L + 8192 + (wc * 4 + i) * 512 + lane * 8);
        }
        asm volatile("s_waitcnt lgkmcnt(0)");
        __builtin_amdgcn_sched_barrier(0);
        __builtin_amdgcn_s_barrier();             // reads done -> next overwrite safe

        #pragma unroll
        for (int i = 0; i < 4; ++i)
            #pragma unroll
            for (int j = 0; j < 4; ++j) {
                if (MODE == 0) {
                    acc[i][j] = __builtin_amdgcn_mfma_f32_16x16x32_bf16(r0[i], r2[j], acc[i][j], 0, 0, 0);
                    acc[i][j] = __builtin_amdgcn_mfma_f32_16x16x32_bf16(r1[i], r2[j], acc[i][j], 0, 0, 0);
                } else {
                    acc[i][j] = __builtin_amdgcn_mfma_f32_16x16x32_bf16(r0[i], r1[j], acc[i][j], 0, 0, 0);
                    acc[i][j] = __builtin_amdgcn_mfma_f32_16x16x32_bf16(r0[i], r2[j], acc[i][j], 0, 0, 0);
                }
            }
    }

    #pragma unroll
    for (int j = 0; j < 4; ++j) {
        int col = bj * 128 + wc * 64 + j * 16 + (lane & 15);
        float bvv = bias[col];
        float g = 0.f, bt = 0.f, mn = 0.f, rs = 0.f;
        if (MODE == 0) {
            g  = gamma[col];
            bt = beta[col];
            mn = mean[col];
            rs = (float)(1.0 / sqrt((double)var[col] + 1e-5));
        }
        #pragma unroll
        for (int i = 0; i < 4; ++i)
            #pragma unroll
            for (int r = 0; r < 4; ++r) {
                int row = bi * 128 + wr * 64 + i * 16 + (lane >> 4) * 4 + r;
                float v = acc[i][j][r] + bvv;
                if (MODE == 0) v = (v - mn) * rs * g + bt;
                C[(size_t)row * NJ + col] = v;
            }
    }
}

// ------------------------------------------------------------------
// Fused distance + argmin, 1-pass (zh*ch), dbuf + counted vmcnt.
// Grid 1024 = 256 row-tiles x 4 code-groups. Block 128 rows x 1024 codes,
// wave 64x128 (4x8 frags). key = se[k] - 2*z.e_k; tie -> lower index.
// se for this group preloaded to LDS (fold reads are lgkm, not vmcnt).
// ------------------------------------------------------------------
__global__ __launch_bounds__(256, 2)
void argmin_mfma(const unsigned short* __restrict__ zh, const unsigned short* __restrict__ ch,
                 const float* __restrict__ se,
                 float* __restrict__ pval, int* __restrict__ pidx)
{
    __shared__ unsigned short lds[24576];   // 2 bufs x 12288 shorts (zh 8 blk | ch 16 blk)
    __shared__ float se_l[1024];
    __shared__ float sv[128][2];
    __shared__ int   si[128][2];
    const int tid = threadIdx.x, wid = tid >> 6, lane = tid & 63;
    const int wr = wid >> 1, wc = wid & 1;
    const int row0 = (int)(blockIdx.x >> 2) * 128;
    const int grp  = (int)(blockIdx.x & 3);

    auto stage = [&](int t, int bufsel) {
        int cc = t >> 4, ks = t & 15;
        int code0 = grp * 1024 + cc * 256;
        unsigned short* dst = lds + bufsel * 12288;
        #pragma unroll
        for (int q = 0; q < 6; ++q) {
            int id = wid * 6 + q;
            const unsigned short* src;
            if (id < 8) {
                src = zh + ((size_t)((row0 >> 4) + id) * 16 + ks) * 512 + lane * 8;
            } else {
                int cb2 = id - 8;
                src = ch + ((size_t)((code0 >> 4) + cb2) * 16 + ks) * 512 + lane * 8;
            }
            gl_lds16(src, dst + id * 512);
        }
    };

    float bv[16];
    int   bi[16];
    #pragma unroll
    for (int s = 0; s < 16; ++s) { bv[s] = FLT_MAX; bi[s] = 0x7fffffff; }

    f32x4 acc[4][8];
    #pragma unroll
    for (int i = 0; i < 4; ++i)
        #pragma unroll
        for (int j = 0; j < 8; ++j) acc[i][j] = (f32x4){0.f, 0.f, 0.f, 0.f};

    // prologue: first tile + se preload (1 gl_lds per wave, 4 KB total)
    stage(0, 0);
    gl_lds16(se + grp * 1024 + wid * 256 + lane * 4, se_l + wid * 256);
    asm volatile("s_waitcnt vmcnt(0)");
    __builtin_amdgcn_s_barrier();

    for (int t = 0; t < 64; ++t) {
        int cur = t & 1;
        if (t < 63) {
            stage(t + 1, cur ^ 1);
            asm volatile("s_waitcnt vmcnt(6)");   // stage(t) complete; t+1 stays in flight
        } else {
            asm volatile("s_waitcnt vmcnt(0)");
        }
        __builtin_amdgcn_s_barrier();             // publish stage(t)

        const unsigned short* L = lds + cur * 12288;
        bf16x8 ah[4], bh[8];
        #pragma unroll
        for (int i = 0; i < 4; ++i)
            ah[i] = *(const bf16x8*)(L + (wr * 4 + i) * 512 + lane * 8);
        #pragma unroll
        for (int j = 0; j < 8; ++j)
            bh[j] = *(const bf16x8*)(L + 4096 + (wc * 8 + j) * 512 + lane * 8);
        asm volatile("s_waitcnt lgkmcnt(0)");
        __builtin_amdgcn_sched_barrier(0);
        __builtin_amdgcn_s_barrier();             // reads done -> overwrite safe

        #pragma unroll
        for (int j = 0; j < 8; ++j)
            #pragma unroll
            for (int i = 0; i < 4; ++i)
                acc[i][j] = __builtin_amdgcn_mfma_f32_16x16x32_bf16(ah[i], bh[j], acc[i][j], 0, 0, 0);

        if ((t & 15) == 15) {   // end of 256-code chunk: fold argmin, reset acc
            int code0 = grp * 1024 + (t >> 4) * 256;
            #pragma unroll
            for (int j = 0; j < 8; ++j) {
                int cidx = wc * 128 + j * 16 + (lane & 15);
                float sev = se_l[(t >> 4) * 256 + cidx];
                int code = code0 + cidx;
                #pragma unroll
                for (int i = 0; i < 4; ++i)
                    #pragma unroll
                    for (int r = 0; r < 4; ++r) {
                        float key = sev - 2.0f * acc[i][j][r];
                        int s = i * 4 + r;
                        if (key < bv[s]) { bv[s] = key; bi[s] = code; }
                        acc[i][j][r] = 0.f;
                    }
            }
        }
    }

    #pragma unroll
    for (int s = 0; s < 16; ++s) {
        #pragma unroll
        for (int off = 1; off < 16; off <<= 1) {
            float ov = __shfl_xor(bv[s], off);
            int   oi = __shfl_xor(bi[s], off);
            if (ov < bv[s] || (ov == bv[s] && oi < bi[s])) { bv[s] = ov; bi[s] = oi; }
        }
    }
    if ((lane & 15) == 0) {
        #pragma unroll
        for (int i = 0; i < 4; ++i)
            #pragma unroll
            for (int r = 0; r < 4; ++r) {
                int row = wr * 64 + i * 16 + (lane >> 4) * 4 + r;
                sv[row][wc] = bv[i * 4 + r];
                si[row][wc] = bi[i * 4 + r];
            }
    }
    __syncthreads();
    if (tid < 128) {
        float v0 = sv[tid][0], v1 = sv[tid][1];
        int   i0 = si[tid][0], i1 = si[tid][1];
        float bvv = v0; int bii = i0;
        if (v1 < v0 || (v1 == v0 && i1 < i0)) { bvv = v1; bii = i1; }
        pval[(size_t)grp * N_FR + row0 + tid] = bvv;
        pidx[(size_t)grp * N_FR + row0 + tid] = bii;
    }
}

// ------------------------------------------------------------------
// Merge 4 code-group partials -> final index; histogram; block-reduced
// loss partial: rowloss = ||z_n||^2 (16 slices) + bestkey_n.
// ------------------------------------------------------------------
__global__ __launch_bounds__(256)
void merge_k(const float* __restrict__ pval, const int* __restrict__ pidx,
             const float* __restrict__ snp,
             int* __restrict__ fidx, int* __restrict__ counts,
             float* __restrict__ lpart)
{
    __shared__ float ls[4];
    int tid = threadIdx.x;
    int n = blockIdx.x * 256 + tid;
    float best = pval[n];
    int   bi   = pidx[n];
    #pragma unroll
    for (int c = 1; c < 4; ++c) {
        float v = pval[(long long)c * N_FR + n];
        int   i = pidx[(long long)c * N_FR + n];
        if (v < best) { best = v; bi = i; }
    }
    fidx[n] = bi;
    atomicAdd(&counts[bi], 1);
    float sn = 0.f;
    #pragma unroll
    for (int c = 0; c < 16; ++c) sn += snp[(long long)c * N_FR + n];
    float rl = sn + best;
    #pragma unroll
    for (int off = 32; off; off >>= 1) rl += __shfl_xor(rl, off);
    if ((tid & 63) == 0) ls[tid >> 6] = rl;
    __syncthreads();
    if (tid == 0) lpart[blockIdx.x] = ls[0] + ls[1] + ls[2] + ls[3];
}

// ------------------------------------------------------------------
// se[k] = sum_d codebook[k][d]^2
// ------------------------------------------------------------------
__global__ __launch_bounds__(256)
void rownorm_k(const float* __restrict__ A, float* __restrict__ sn)
{
    int row  = blockIdx.x * 4 + (threadIdx.x >> 6);
    int lane = threadIdx.x & 63;
    const float4* p = (const float4*)(A + (long long)row * D_DIM + lane * 8);
    float4 a = p[0], b = p[1];
    float s = a.x*a.x + a.y*a.y + a.z*a.z + a.w*a.w
            + b.x*b.x + b.y*b.y + b.z*b.z + b.w*b.w;
    #pragma unroll
    for (int off = 32; off; off >>= 1) s += __shfl_xor(s, off);
    if (lane == 0) sn[row] = s;
}

__global__ __launch_bounds__(256)
void gather_k(const float* __restrict__ DC, const int* __restrict__ fidx,
              float* __restrict__ outp)
{
    int n = blockIdx.x;
    int id = fidx[n];
    float4 v = ((const float4*)(DC + (long long)id * M_DIM))[threadIdx.x];
    ((float4*)(outp + (long long)n * M_DIM))[threadIdx.x] = v;
}

// ------------------------------------------------------------------
// One-pass encodings writer: zeros + one-hot, coalesced float4.
// ------------------------------------------------------------------
__global__ __launch_bounds__(256)
void enc_write(const int* __restrict__ fidx, float* __restrict__ enc)
{
    int n    = blockIdx.x * 4 + (threadIdx.x >> 6);
    int lane = threadIdx.x & 63;
    int idx  = fidx[n];
    float4* row = (float4*)(enc + (size_t)n * K_CB);
    #pragma unroll
    for (int c = 0; c < 16; ++c) {
        int p = c * 64 + lane;
        int b4 = p * 4;
        float4 v;
        v.x = (idx == b4 + 0) ? 1.0f : 0.0f;
        v.y = (idx == b4 + 1) ? 1.0f : 0.0f;
        v.z = (idx == b4 + 2) ? 1.0f : 0.0f;
        v.w = (idx == b4 + 3) ? 1.0f : 0.0f;
        row[p] = v;
    }
}

__global__ __launch_bounds__(256)
void fin_k(const int* __restrict__ counts, const float* __restrict__ lpart,
           float* __restrict__ scal)
{
    __shared__ double sh[4], lh[4];
    int tid = threadIdx.x;
    double s = 0.0;
    for (int k = tid; k < K_CB; k += 256) {
        double p = (double)counts[k] / (double)N_FR;
        s += p * log(p + 1e-10);
    }
    double l = (tid < 128) ? (double)lpart[tid] : 0.0;
    #pragma unroll
    for (int off = 32; off; off >>= 1) {
        s += __shfl_xor(s, off);
        l += __shfl_xor(l, off);
    }
    if ((tid & 63) == 0) { sh[tid >> 6] = s; lh[tid >> 6] = l; }
    __syncthreads();
    if (tid == 0) {
        double tot = sh[0] + sh[1] + sh[2] + sh[3];
        double L   = lh[0] + lh[1] + lh[2] + lh[3];
        scal[0] = (float)(0.25 * L / ((double)N_FR * (double)D_DIM));
        scal[1] = (float)exp(-tot);
    }
}

extern "C" void kernel_launch(void* const* d_in, const int* in_sizes, int n_in,
                              void* d_out, int out_size, void* d_ws, size_t ws_size,
                              hipStream_t stream)
{
    (void)in_sizes; (void)n_in; (void)out_size; (void)ws_size;
    const float* x        = (const float*)d_in[0];
    const float* enc_w    = (const float*)d_in[1];
    const float* enc_b    = (const float*)d_in[2];
    const float* bn_gamma = (const float*)d_in[3];
    const float* bn_beta  = (const float*)d_in[4];
    const float* bn_mean  = (const float*)d_in[5];
    const float* bn_var   = (const float*)d_in[6];
    const float* cb       = (const float*)d_in[7];
    const float* dec_w    = (const float*)d_in[8];
    const float* dec_b    = (const float*)d_in[9];

    float* outp = (float*)d_out;
    float* z    = outp + Z_OFF;
    float* dc   = outp + DC_OFF;
    unsigned short* xh  = (unsigned short*)(outp + XH_OFF);
    unsigned short* xl  = (unsigned short*)(outp + XL_OFF);
    unsigned short* whp = (unsigned short*)(outp + WH_OFF);
    unsigned short* chp = (unsigned short*)(outp + CH_OFF);
    unsigned short* zhp = (unsigned short*)(outp + ZH_OFF);
    float* pval = outp + PV_OFF;
    int*   pidx = (int*)(outp + PI_OFF);
    unsigned short* dwh = (unsigned short*)(outp + DWH_OFF);
    unsigned short* dwl = (unsigned short*)(outp + DWL_OFF);
    float* snp   = outp + SNP_OFF;
    float* lpart = outp + LP_OFF;

    char*   wsb    = (char*)d_ws;
    int*    fidx   = (int*)wsb;                    // N ints
    int*    counts = (int*)(wsb + 131072);         // K ints
    float*  se     = (float*)(wsb + 147456);       // K floats

    hipMemsetAsync(counts, 0, 16384, stream);      // counts only

    // input conversions (x: hi+lo, enc_w: hi, cb: hi, dec_w: hi+lo)
    conv_all<<<dim3(17920), 256, 0, stream>>>(x, enc_w, cb, dec_w,
        xh, xl, whp, chp, dwh, dwl);
    rownorm_k<<<dim3(K_CB / 4), 256, 0, stream>>>(cb, se);

    // encoder (2-pass split MFMA, dbuf + counted vmcnt) -> z fp32 with BN
    gemm2<0><<<dim3(1024), 256, 0, stream>>>(xh, xl, whp,
        enc_b, bn_gamma, bn_beta, bn_mean, bn_var, z, 256, 32, D_DIM);
    // z -> packed zh + row-norm partials
    conv_z<<<dim3(8192), 256, 0, stream>>>(z, zhp, snp);

    // decoded codebook (2-pass B-split MFMA): dec_cb = cb @ dec_w.T + dec_b
    gemm2<1><<<dim3(256), 256, 0, stream>>>(chp, dwh, dwl,
        dec_b, nullptr, nullptr, nullptr, nullptr, dc, 32, 16, M_DIM);

    // fused distances + argmin (1-pass, dbuf + counted vmcnt)
    argmin_mfma<<<dim3(1024), 256, 0, stream>>>(zhp, chp, se, pval, pidx);
    merge_k<<<dim3(N_FR / 256), 256, 0, stream>>>(pval, pidx, snp, fidx, counts, lpart);

    gather_k<<<dim3(N_FR), 256, 0, stream>>>(dc, fidx, outp);
    fin_k<<<dim3(1), 256, 0, stream>>>(counts, lpart, outp + LOSS_OFF);

    // final one-pass encodings write (wipes all scratch in that region)
    enc_write<<<dim3(N_FR / 4), 256, 0, stream>>>(fidx, outp + ENC_OFF);
}

// Round 10
// 660.515 us; speedup vs baseline: 1.1165x; 1.1165x over previous
//
#include <hip/hip_runtime.h>
#include <math.h>
#include <float.h>

#define N_FR 32768
#define M_DIM 1024
#define D_DIM 512
#define K_CB 4096

// ---- d_out layout (floats) ----
static const long long OUT_ELEMS = (long long)N_FR * M_DIM;
static const long long LOSS_OFF  = OUT_ELEMS;
static const long long ENC_OFF   = OUT_ELEMS + 2;
// scratch inside the encodings region (all consumed before enc_write)
static const long long Z_OFF   = ENC_OFF + 2;                           // fp32 z [N][D]
static const long long DC_OFF  = Z_OFF  + (long long)N_FR * D_DIM;      // fp32 dec_cb [K][M]
static const long long XH_OFF  = DC_OFF + (long long)K_CB * M_DIM;
static const long long XL_OFF  = XH_OFF + (long long)N_FR * M_DIM / 2;
static const long long WH_OFF  = XL_OFF + (long long)N_FR * M_DIM / 2;
static const long long WL_OFF  = WH_OFF + (long long)D_DIM * M_DIM / 2;
static const long long CH_OFF  = WL_OFF + (long long)D_DIM * M_DIM / 2;
static const long long CL_OFF  = CH_OFF + (long long)K_CB * D_DIM / 2;
static const long long ZH_OFF  = CL_OFF + (long long)K_CB * D_DIM / 2;
static const long long ZL_OFF  = ZH_OFF + (long long)N_FR * D_DIM / 2;
static const long long PV_OFF  = ZL_OFF + (long long)N_FR * D_DIM / 2;  // partial best val [4][N]
static const long long PI_OFF  = PV_OFF + 4LL * N_FR;                   // partial best idx [4][N]
static const long long DWH_OFF = PI_OFF + 4LL * N_FR;                   // dec_w hi
static const long long DWL_OFF = DWH_OFF + (long long)M_DIM * D_DIM / 2;// dec_w lo
static const long long SNP_OFF = DWL_OFF + (long long)M_DIM * D_DIM / 2;// ||z||^2 partials [16][N]
static const long long LP_OFF  = SNP_OFF + 16LL * N_FR;                 // loss partials [128]

typedef __attribute__((ext_vector_type(8))) short bf16x8;
typedef __attribute__((ext_vector_type(8))) unsigned short u16x8;
typedef __attribute__((ext_vector_type(4))) float f32x4;

__device__ __forceinline__ unsigned short f2bf(float f) {
    unsigned u = __float_as_uint(f);
    return (unsigned short)((u + 0x7fffu + ((u >> 16) & 1u)) >> 16);
}
__device__ __forceinline__ float bf2f(unsigned short h) {
    return __uint_as_float(((unsigned)h) << 16);
}
__device__ __forceinline__ void gl_lds16(const unsigned short* g, unsigned short* l) {
    __builtin_amdgcn_global_load_lds(
        (const __attribute__((address_space(1))) unsigned int*)g,
        (__attribute__((address_space(3))) unsigned int*)l,
        16, 0, 0);
}

// ------------------------------------------------------------------
// fp32 [R][C] -> hi/lo bf16, fragment-blocked (round-4 mapping):
// flat16 = b*512 + lane*8 + j,  b = (r>>4)*(C/32) + (c>>5),
// lane = (r&15) + 16*((c>>3)&3), j = c&7.
// ------------------------------------------------------------------
__device__ __forceinline__ void conv_body(const float* in, unsigned short* hi,
                                          unsigned short* lo, int C, int KC, int w)
{
    int lane = threadIdx.x & 63;
    int bn = w / KC, ck = w % KC;
    int r = bn * 16 + (lane & 15);
    int c = ck * 32 + (lane >> 4) * 8;
    const float4* p = (const float4*)&in[(size_t)r * C + c];
    float4 v0 = p[0], v1 = p[1];
    float f[8] = {v0.x, v0.y, v0.z, v0.w, v1.x, v1.y, v1.z, v1.w};
    u16x8 hv, lv;
    #pragma unroll
    for (int j = 0; j < 8; ++j) {
        unsigned short h = f2bf(f[j]);
        hv[j] = h;
        lv[j] = f2bf(f[j] - bf2f(h));
    }
    size_t o = (size_t)w * 512 + lane * 8;
    *(u16x8*)&hi[o] = hv;
    *(u16x8*)&lo[o] = lv;
}

// all four input conversions in ONE dispatch (block-uniform select)
__global__ __launch_bounds__(256)
void conv_all(const float* __restrict__ x,  const float* __restrict__ ew,
              const float* __restrict__ cb, const float* __restrict__ dw,
              unsigned short* __restrict__ xh,  unsigned short* __restrict__ xl,
              unsigned short* __restrict__ wh,  unsigned short* __restrict__ wl,
              unsigned short* __restrict__ ch,  unsigned short* __restrict__ cl,
              unsigned short* __restrict__ dwh, unsigned short* __restrict__ dwl)
{
    int b = blockIdx.x;
    const float* in; unsigned short* hi; unsigned short* lo; int C; int w0;
    if (b < 16384)      { in = x;  hi = xh;  lo = xl;  C = 1024; w0 = b; }
    else if (b < 16640) { in = ew; hi = wh;  lo = wl;  C = 1024; w0 = b - 16384; }
    else if (b < 17664) { in = cb; hi = ch;  lo = cl;  C = 512;  w0 = b - 16640; }
    else                { in = dw; hi = dwh; lo = dwl; C = 512;  w0 = b - 17664; }
    int KC = C / 32;
    conv_body(in, hi, lo, C, KC, w0 * 4 + (threadIdx.x >> 6));
}

// ------------------------------------------------------------------
// z -> packed zh + zl + per-chunk row-norm partials snp[ck][row].
// (fuses the old conv_split(z) and rownorm_k(z): z read ONCE)
// ------------------------------------------------------------------
__global__ __launch_bounds__(256)
void conv_z(const float* __restrict__ z, unsigned short* __restrict__ zh,
            unsigned short* __restrict__ zl, float* __restrict__ snp)
{
    int w = blockIdx.x * 4 + (threadIdx.x >> 6);
    int lane = threadIdx.x & 63;
    int bn = w >> 4, ck = w & 15;            // KC = 512/32 = 16
    int r = bn * 16 + (lane & 15);
    int c = ck * 32 + (lane >> 4) * 8;
    const float4* p = (const float4*)&z[(size_t)r * D_DIM + c];
    float4 v0 = p[0], v1 = p[1];
    float f[8] = {v0.x, v0.y, v0.z, v0.w, v1.x, v1.y, v1.z, v1.w};
    u16x8 hv, lv;
    float s = 0.f;
    #pragma unroll
    for (int j = 0; j < 8; ++j) {
        unsigned short h = f2bf(f[j]);
        hv[j] = h;
        lv[j] = f2bf(f[j] - bf2f(h));
        s = fmaf(f[j], f[j], s);
    }
    size_t o = (size_t)w * 512 + lane * 8;
    *(u16x8*)&zh[o] = hv;
    *(u16x8*)&zl[o] = lv;
    s += __shfl_xor(s, 16);
    s += __shfl_xor(s, 32);                   // 4 lanes of same row now equal
    if ((lane >> 4) == 0) snp[(size_t)ck * N_FR + r] = s;
}

// ------------------------------------------------------------------
// Packed bf16 3-pass split MFMA GEMM (round-6 verbatim).
// 128x128 tile, 4 waves (2x2), wave 64x64 (4x4 frags of 16x16x32).
// EPI==0: bias+BN epilogue (encoder). EPI==1: bias only (dec codebook).
// ------------------------------------------------------------------
template<int EPI>
__global__ __launch_bounds__(256)
void gemm_pack(const unsigned short* __restrict__ ah_, const unsigned short* __restrict__ al_,
               const unsigned short* __restrict__ bh_, const unsigned short* __restrict__ bl_,
               const float* __restrict__ bias, const float* __restrict__ gamma,
               const float* __restrict__ beta, const float* __restrict__ mean,
               const float* __restrict__ var, float* __restrict__ C,
               int nbi, int nkb, int NJ)
{
    __shared__ unsigned short lds[16384];
    const int tid = threadIdx.x, wid = tid >> 6, lane = tid & 63;
    const int wr = wid >> 1, wc = wid & 1;
    const int bi = blockIdx.x % nbi, bj = blockIdx.x / nbi;

    f32x4 acc[4][4];
    #pragma unroll
    for (int i = 0; i < 4; ++i)
        #pragma unroll
        for (int j = 0; j < 4; ++j) acc[i][j] = (f32x4){0.f, 0.f, 0.f, 0.f};

    for (int ks = 0; ks < nkb; ++ks) {
        __syncthreads();
        #pragma unroll
        for (int q = 0; q < 8; ++q) {
            int id = wid * 8 + q;
            int arr = id >> 3, rb = id & 7;
            const unsigned short* base = arr == 0 ? ah_ : arr == 1 ? al_ : arr == 2 ? bh_ : bl_;
            size_t b = (size_t)((arr < 2 ? bi : bj) * 8 + rb) * nkb + ks;
            gl_lds16(base + b * 512 + lane * 8, lds + id * 512);
        }
        __syncthreads();
        bf16x8 ah[4], al[4], bh[4], bl[4];
        #pragma unroll
        for (int i = 0; i < 4; ++i) {
            ah[i] = *(const bf16x8*)(lds + (4 * wr + i) * 512 + lane * 8);
            al[i] = *(const bf16x8*)(lds + 4096 + (4 * wr + i) * 512 + lane * 8);
        }
        #pragma unroll
        for (int j = 0; j < 4; ++j) {
            bh[j] = *(const bf16x8*)(lds + 8192  + (4 * wc + j) * 512 + lane * 8);
            bl[j] = *(const bf16x8*)(lds + 12288 + (4 * wc + j) * 512 + lane * 8);
        }
        #pragma unroll
        for (int i = 0; i < 4; ++i)
            #pragma unroll
            for (int j = 0; j < 4; ++j) {
                acc[i][j] = __builtin_amdgcn_mfma_f32_16x16x32_bf16(ah[i], bh[j], acc[i][j], 0, 0, 0);
                acc[i][j] = __builtin_amdgcn_mfma_f32_16x16x32_bf16(ah[i], bl[j], acc[i][j], 0, 0, 0);
                acc[i][j] = __builtin_amdgcn_mfma_f32_16x16x32_bf16(al[i], bh[j], acc[i][j], 0, 0, 0);
            }
    }
    #pragma unroll
    for (int j = 0; j < 4; ++j) {
        int col = bj * 128 + wc * 64 + j * 16 + (lane & 15);
        float bvv = bias[col];
        float g = 0.f, bt = 0.f, mn = 0.f, rs = 0.f;
        if (EPI == 0) {
            g  = gamma[col];
            bt = beta[col];
            mn = mean[col];
            rs = (float)(1.0 / sqrt((double)var[col] + 1e-5));
        }
        #pragma unroll
        for (int i = 0; i < 4; ++i)
            #pragma unroll
            for (int r = 0; r < 4; ++r) {
                int row = bi * 128 + wr * 64 + i * 16 + (lane >> 4) * 4 + r;
                float v = acc[i][j][r] + bvv;
                if (EPI == 0) v = (v - mn) * rs * g + bt;
                C[(size_t)row * NJ + col] = v;
            }
    }
}

// ------------------------------------------------------------------
// Fused distance + argmin (round-6 structure: 2-pass zh*ch + zl*ch,
// double-buffered, one barrier/step). Grid 1024 decoded grp-OUTER:
// grp = bid>>8, rt = bid&255 -> the 4 blocks sharing a z row-tile are
// 256 apart = SAME XCD -> z tile cached once per L2.
// key = se[k] - 2*z.e_k ; tie -> lower index everywhere.
// ------------------------------------------------------------------
__global__ __launch_bounds__(256, 2)
void argmin_mfma(const unsigned short* __restrict__ zh, const unsigned short* __restrict__ zl,
                 const unsigned short* __restrict__ ch,
                 const float* __restrict__ se,
                 float* __restrict__ pval, int* __restrict__ pidx)
{
    __shared__ unsigned short lds[32768];   // 64KB = 2 x 32KB buffers
    __shared__ float sv[128][2];
    __shared__ int   si[128][2];
    const int tid = threadIdx.x, wid = tid >> 6, lane = tid & 63;
    const int wr = wid >> 1, wc = wid & 1;
    const int row0 = (int)(blockIdx.x & 255) * 128;
    const int grp  = (int)(blockIdx.x >> 8);

    // per-buffer layout (shorts): zh [0,4096) zl [4096,8192) ch [8192,16384)
    auto stage = [&](int t, int bufsel) {
        int cc = t >> 4, ks = t & 15;
        int code0 = grp * 1024 + cc * 256;
        unsigned short* dst = lds + bufsel * 16384;
        #pragma unroll
        for (int q = 0; q < 8; ++q) {
            int id = wid * 8 + q;
            const unsigned short* src;
            if (id < 16) {
                int a = id >> 3, rb = id & 7;
                src = (a ? zl : zh) + ((size_t)((row0 >> 4) + rb) * 16 + ks) * 512 + lane * 8;
            } else {
                int cb2 = id - 16;
                src = ch + ((size_t)((code0 >> 4) + cb2) * 16 + ks) * 512 + lane * 8;
            }
            gl_lds16(src, dst + id * 512);
        }
    };

    float bv[16];
    int   bi[16];
    #pragma unroll
    for (int s = 0; s < 16; ++s) { bv[s] = FLT_MAX; bi[s] = 0x7fffffff; }

    f32x4 acc[4][8];
    #pragma unroll
    for (int i = 0; i < 4; ++i)
        #pragma unroll
        for (int j = 0; j < 8; ++j) acc[i][j] = (f32x4){0.f, 0.f, 0.f, 0.f};

    stage(0, 0);
    __syncthreads();

    for (int t = 0; t < 64; ++t) {
        int cur = t & 1;
        if (t < 63) stage(t + 1, cur ^ 1);          // prefetch next step
        const unsigned short* L = lds + cur * 16384;
        bf16x8 ah[4], al[4];
        #pragma unroll
        for (int i = 0; i < 4; ++i) {
            ah[i] = *(const bf16x8*)(L + (wr * 4 + i) * 512 + lane * 8);
            al[i] = *(const bf16x8*)(L + 4096 + (wr * 4 + i) * 512 + lane * 8);
        }
        #pragma unroll
        for (int j = 0; j < 8; ++j) {
            bf16x8 bhj = *(const bf16x8*)(L + 8192 + (wc * 8 + j) * 512 + lane * 8);
            #pragma unroll
            for (int i = 0; i < 4; ++i) {
                acc[i][j] = __builtin_amdgcn_mfma_f32_16x16x32_bf16(ah[i], bhj, acc[i][j], 0, 0, 0);
                acc[i][j] = __builtin_amdgcn_mfma_f32_16x16x32_bf16(al[i], bhj, acc[i][j], 0, 0, 0);
            }
        }
        if ((t & 15) == 15) {   // end of a 256-code chunk: fold argmin, reset acc
            int code0 = grp * 1024 + (t >> 4) * 256;
            #pragma unroll
            for (int j = 0; j < 8; ++j) {
                int code = code0 + wc * 128 + j * 16 + (lane & 15);
                float sev = se[code];
                #pragma unroll
                for (int i = 0; i < 4; ++i)
                    #pragma unroll
                    for (int r = 0; r < 4; ++r) {
                        float key = sev - 2.0f * acc[i][j][r];
                        int s = i * 4 + r;
                        if (key < bv[s]) { bv[s] = key; bi[s] = code; }
                        acc[i][j][r] = 0.f;
                    }
            }
        }
        __syncthreads();   // drains this step's prefetch (vmcnt0) + lds reads
    }

    // butterfly across the 16 code-lanes (tie -> lower index)
    #pragma unroll
    for (int s = 0; s < 16; ++s) {
        #pragma unroll
        for (int off = 1; off < 16; off <<= 1) {
            float ov = __shfl_xor(bv[s], off);
            int   oi = __shfl_xor(bi[s], off);
            if (ov < bv[s] || (ov == bv[s] && oi < bi[s])) { bv[s] = ov; bi[s] = oi; }
        }
    }
    if ((lane & 15) == 0) {
        #pragma unroll
        for (int i = 0; i < 4; ++i)
            #pragma unroll
            for (int r = 0; r < 4; ++r) {
                int row = wr * 64 + i * 16 + (lane >> 4) * 4 + r;
                sv[row][wc] = bv[i * 4 + r];
                si[row][wc] = bi[i * 4 + r];
            }
    }
    __syncthreads();
    if (tid < 128) {
        float v0 = sv[tid][0], v1 = sv[tid][1];
        int   i0 = si[tid][0], i1 = si[tid][1];
        float bvv = v0; int bii = i0;
        if (v1 < v0 || (v1 == v0 && i1 < i0)) { bvv = v1; bii = i1; }
        pval[(size_t)grp * N_FR + row0 + tid] = bvv;
        pidx[(size_t)grp * N_FR + row0 + tid] = bii;
    }
}

// ------------------------------------------------------------------
// Merge 4 code-group partials -> final index; histogram; block-reduced
// loss partial: rowloss = ||z_n||^2 (16 slices) + bestkey_n.
// ------------------------------------------------------------------
__global__ __launch_bounds__(256)
void merge_k(const float* __restrict__ pval, const int* __restrict__ pidx,
             const float* __restrict__ snp,
             int* __restrict__ fidx, int* __restrict__ counts,
             float* __restrict__ lpart)
{
    __shared__ float ls[4];
    int tid = threadIdx.x;
    int n = blockIdx.x * 256 + tid;
    float best = pval[n];
    int   bi   = pidx[n];
    #pragma unroll
    for (int c = 1; c < 4; ++c) {
        float v = pval[(long long)c * N_FR + n];
        int   i = pidx[(long long)c * N_FR + n];
        if (v < best) { best = v; bi = i; }   // groups ascend in index; tie keeps lower
    }
    fidx[n] = bi;
    atomicAdd(&counts[bi], 1);
    float sn = 0.f;
    #pragma unroll
    for (int c = 0; c < 16; ++c) sn += snp[(long long)c * N_FR + n];
    float rl = sn + best;
    #pragma unroll
    for (int off = 32; off; off >>= 1) rl += __shfl_xor(rl, off);
    if ((tid & 63) == 0) ls[tid >> 6] = rl;
    __syncthreads();
    if (tid == 0) lpart[blockIdx.x] = ls[0] + ls[1] + ls[2] + ls[3];
}

// ------------------------------------------------------------------
// se[k] = sum_d codebook[k][d]^2
// ------------------------------------------------------------------
__global__ __launch_bounds__(256)
void rownorm_k(const float* __restrict__ A, float* __restrict__ sn)
{
    int row  = blockIdx.x * 4 + (threadIdx.x >> 6);
    int lane = threadIdx.x & 63;
    const float4* p = (const float4*)(A + (long long)row * D_DIM + lane * 8);
    float4 a = p[0], b = p[1];
    float s = a.x*a.x + a.y*a.y + a.z*a.z + a.w*a.w
            + b.x*b.x + b.y*b.y + b.z*b.z + b.w*b.w;
    #pragma unroll
    for (int off = 32; off; off >>= 1) s += __shfl_xor(s, off);
    if (lane == 0) sn[row] = s;
}

__global__ __launch_bounds__(256)
void gather_k(const float* __restrict__ DC, const int* __restrict__ fidx,
              float* __restrict__ outp)
{
    int n = blockIdx.x;
    int id = fidx[n];
    float4 v = ((const float4*)(DC + (long long)id * M_DIM))[threadIdx.x];
    ((float4*)(outp + (long long)n * M_DIM))[threadIdx.x] = v;
}

// ------------------------------------------------------------------
// One-pass encodings writer: zeros + one-hot, coalesced nontemporal f32x4.
// ------------------------------------------------------------------
__global__ __launch_bounds__(256)
void enc_write(const int* __restrict__ fidx, float* __restrict__ enc)
{
    int n    = blockIdx.x * 4 + (threadIdx.x >> 6);
    int lane = threadIdx.x & 63;
    int idx  = fidx[n];
    f32x4* row = (f32x4*)(enc + (size_t)n * K_CB);
    #pragma unroll
    for (int c = 0; c < 16; ++c) {
        int p = c * 64 + lane;
        int b4 = p * 4;
        f32x4 v;
        v.x = (idx == b4 + 0) ? 1.0f : 0.0f;
        v.y = (idx == b4 + 1) ? 1.0f : 0.0f;
        v.z = (idx == b4 + 2) ? 1.0f : 0.0f;
        v.w = (idx == b4 + 3) ? 1.0f : 0.0f;
        __builtin_nontemporal_store(v, &row[p]);
    }
}

__global__ __launch_bounds__(256)
void fin_k(const int* __restrict__ counts, const float* __restrict__ lpart,
           float* __restrict__ scal)
{
    __shared__ double sh[4], lh[4];
    int tid = threadIdx.x;
    double s = 0.0;
    for (int k = tid; k < K_CB; k += 256) {
        double p = (double)counts[k] / (double)N_FR;
        s += p * log(p + 1e-10);
    }
    double l = (tid < 128) ? (double)lpart[tid] : 0.0;
    #pragma unroll
    for (int off = 32; off; off >>= 1) {
        s += __shfl_xor(s, off);
        l += __shfl_xor(l, off);
    }
    if ((tid & 63) == 0) { sh[tid >> 6] = s; lh[tid >> 6] = l; }
    __syncthreads();
    if (tid == 0) {
        double tot = sh[0] + sh[1] + sh[2] + sh[3];
        double L   = lh[0] + lh[1] + lh[2] + lh[3];
        scal[0] = (float)(0.25 * L / ((double)N_FR * (double)D_DIM));
        scal[1] = (float)exp(-tot);
    }
}

extern "C" void kernel_launch(void* const* d_in, const int* in_sizes, int n_in,
                              void* d_out, int out_size, void* d_ws, size_t ws_size,
                              hipStream_t stream)
{
    (void)in_sizes; (void)n_in; (void)out_size; (void)ws_size;
    const float* x        = (const float*)d_in[0];
    const float* enc_w    = (const float*)d_in[1];
    const float* enc_b    = (const float*)d_in[2];
    const float* bn_gamma = (const float*)d_in[3];
    const float* bn_beta  = (const float*)d_in[4];
    const float* bn_mean  = (const float*)d_in[5];
    const float* bn_var   = (const float*)d_in[6];
    const float* cb       = (const float*)d_in[7];
    const float* dec_w    = (const float*)d_in[8];
    const float* dec_b    = (const float*)d_in[9];

    float* outp = (float*)d_out;
    float* z    = outp + Z_OFF;
    float* dc   = outp + DC_OFF;
    unsigned short* xh  = (unsigned short*)(outp + XH_OFF);
    unsigned short* xl  = (unsigned short*)(outp + XL_OFF);
    unsigned short* whp = (unsigned short*)(outp + WH_OFF);
    unsigned short* wlp = (unsigned short*)(outp + WL_OFF);
    unsigned short* chp = (unsigned short*)(outp + CH_OFF);
    unsigned short* clp = (unsigned short*)(outp + CL_OFF);
    unsigned short* zhp = (unsigned short*)(outp + ZH_OFF);
    unsigned short* zlp = (unsigned short*)(outp + ZL_OFF);
    float* pval = outp + PV_OFF;
    int*   pidx = (int*)(outp + PI_OFF);
    unsigned short* dwh = (unsigned short*)(outp + DWH_OFF);
    unsigned short* dwl = (unsigned short*)(outp + DWL_OFF);
    float* snp   = outp + SNP_OFF;
    float* lpart = outp + LP_OFF;

    char*   wsb    = (char*)d_ws;
    int*    fidx   = (int*)wsb;                    // N ints
    int*    counts = (int*)(wsb + 131072);         // K ints
    float*  se     = (float*)(wsb + 147456);       // K floats

    hipMemsetAsync(counts, 0, 16384, stream);      // counts only

    // all four input conversions in one dispatch
    conv_all<<<dim3(17920), 256, 0, stream>>>(x, enc_w, cb, dec_w,
        xh, xl, whp, wlp, chp, clp, dwh, dwl);
    rownorm_k<<<dim3(K_CB / 4), 256, 0, stream>>>(cb, se);

    // encoder (MFMA, 3-pass bf16) -> z fp32
    gemm_pack<0><<<dim3(1024), 256, 0, stream>>>(xh, xl, whp, wlp,
        enc_b, bn_gamma, bn_beta, bn_mean, bn_var, z, 256, 32, D_DIM);
    // z -> packed zh/zl + row-norm partials (single pass over z)
    conv_z<<<dim3(8192), 256, 0, stream>>>(z, zhp, zlp, snp);

    // decoded codebook (MFMA): dec_cb = codebook @ dec_w.T + dec_b
    gemm_pack<1><<<dim3(256), 256, 0, stream>>>(chp, clp, dwh, dwl,
        dec_b, nullptr, nullptr, nullptr, nullptr, dc, 32, 16, M_DIM);

    // fused distances + argmin (2-pass, dbuf, grp-outer XCD-friendly decode)
    argmin_mfma<<<dim3(1024), 256, 0, stream>>>(zhp, zlp, chp, se, pval, pidx);
    merge_k<<<dim3(N_FR / 256), 256, 0, stream>>>(pval, pidx, snp, fidx, counts, lpart);

    gather_k<<<dim3(N_FR), 256, 0, stream>>>(dc, fidx, outp);
    fin_k<<<dim3(1), 256, 0, stream>>>(counts, lpart, outp + LOSS_OFF);

    // final one-pass encodings write (wipes all scratch in that region)
    enc_write<<<dim3(N_FR / 4), 256, 0, stream>>>(fidx, outp + ENC_OFF);
}

// Round 11
// 647.934 us; speedup vs baseline: 1.1382x; 1.0194x over previous
//
#include <hip/hip_runtime.h>
#include <math.h>
#include <float.h>

#define N_FR 32768
#define M_DIM 1024
#define D_DIM 512
#define K_CB 4096

// ---- d_out layout (floats) ----
static const long long OUT_ELEMS = (long long)N_FR * M_DIM;
static const long long LOSS_OFF  = OUT_ELEMS;
static const long long ENC_OFF   = OUT_ELEMS + 2;
// scratch inside the encodings region (all consumed before enc_write)
static const long long Z_OFF   = ENC_OFF + 2;                           // fp32 z [N][D]
static const long long DC_OFF  = Z_OFF  + (long long)N_FR * D_DIM;      // fp32 dec_cb [K][M]
static const long long XH_OFF  = DC_OFF + (long long)K_CB * M_DIM;
static const long long XL_OFF  = XH_OFF + (long long)N_FR * M_DIM / 2;
static const long long WH_OFF  = XL_OFF + (long long)N_FR * M_DIM / 2;
static const long long WL_OFF  = WH_OFF + (long long)D_DIM * M_DIM / 2;
static const long long CH_OFF  = WL_OFF + (long long)D_DIM * M_DIM / 2;
static const long long CL_OFF  = CH_OFF + (long long)K_CB * D_DIM / 2;
static const long long ZH_OFF  = CL_OFF + (long long)K_CB * D_DIM / 2;
static const long long ZL_OFF  = ZH_OFF + (long long)N_FR * D_DIM / 2;
static const long long PV_OFF  = ZL_OFF + (long long)N_FR * D_DIM / 2;  // partial best val [4][N]
static const long long PI_OFF  = PV_OFF + 4LL * N_FR;                   // partial best idx [4][N]
static const long long DWH_OFF = PI_OFF + 4LL * N_FR;                   // dec_w hi
static const long long DWL_OFF = DWH_OFF + (long long)M_DIM * D_DIM / 2;// dec_w lo
static const long long SNP_OFF = DWL_OFF + (long long)M_DIM * D_DIM / 2;// ||z||^2 partials [16][N]
static const long long LP_OFF  = SNP_OFF + 16LL * N_FR;                 // loss partials [128]

typedef __attribute__((ext_vector_type(8))) short bf16x8;
typedef __attribute__((ext_vector_type(8))) unsigned short u16x8;
typedef __attribute__((ext_vector_type(4))) float f32x4;

__device__ __forceinline__ unsigned short f2bf(float f) {
    unsigned u = __float_as_uint(f);
    return (unsigned short)((u + 0x7fffu + ((u >> 16) & 1u)) >> 16);
}
__device__ __forceinline__ float bf2f(unsigned short h) {
    return __uint_as_float(((unsigned)h) << 16);
}
__device__ __forceinline__ void gl_lds16(const unsigned short* g, unsigned short* l) {
    __builtin_amdgcn_global_load_lds(
        (const __attribute__((address_space(1))) unsigned int*)g,
        (__attribute__((address_space(3))) unsigned int*)l,
        16, 0, 0);
}

// ------------------------------------------------------------------
// fp32 [R][C] -> hi/lo bf16, fragment-blocked (round-4 mapping):
// flat16 = b*512 + lane*8 + j,  b = (r>>4)*(C/32) + (c>>5),
// lane = (r&15) + 16*((c>>3)&3), j = c&7.
// ------------------------------------------------------------------
__device__ __forceinline__ void conv_body(const float* in, unsigned short* hi,
                                          unsigned short* lo, int C, int KC, int w)
{
    int lane = threadIdx.x & 63;
    int bn = w / KC, ck = w % KC;
    int r = bn * 16 + (lane & 15);
    int c = ck * 32 + (lane >> 4) * 8;
    const float4* p = (const float4*)&in[(size_t)r * C + c];
    float4 v0 = p[0], v1 = p[1];
    float f[8] = {v0.x, v0.y, v0.z, v0.w, v1.x, v1.y, v1.z, v1.w};
    u16x8 hv, lv;
    #pragma unroll
    for (int j = 0; j < 8; ++j) {
        unsigned short h = f2bf(f[j]);
        hv[j] = h;
        lv[j] = f2bf(f[j] - bf2f(h));
    }
    size_t o = (size_t)w * 512 + lane * 8;
    *(u16x8*)&hi[o] = hv;
    *(u16x8*)&lo[o] = lv;
}

// all four input conversions in ONE dispatch (block-uniform select)
__global__ __launch_bounds__(256)
void conv_all(const float* __restrict__ x,  const float* __restrict__ ew,
              const float* __restrict__ cb, const float* __restrict__ dw,
              unsigned short* __restrict__ xh,  unsigned short* __restrict__ xl,
              unsigned short* __restrict__ wh,  unsigned short* __restrict__ wl,
              unsigned short* __restrict__ ch,  unsigned short* __restrict__ cl,
              unsigned short* __restrict__ dwh, unsigned short* __restrict__ dwl)
{
    int b = blockIdx.x;
    const float* in; unsigned short* hi; unsigned short* lo; int C; int w0;
    if (b < 16384)      { in = x;  hi = xh;  lo = xl;  C = 1024; w0 = b; }
    else if (b < 16640) { in = ew; hi = wh;  lo = wl;  C = 1024; w0 = b - 16384; }
    else if (b < 17664) { in = cb; hi = ch;  lo = cl;  C = 512;  w0 = b - 16640; }
    else                { in = dw; hi = dwh; lo = dwl; C = 512;  w0 = b - 17664; }
    int KC = C / 32;
    conv_body(in, hi, lo, C, KC, w0 * 4 + (threadIdx.x >> 6));
}

// ------------------------------------------------------------------
// z -> packed zh + zl + per-chunk row-norm partials snp[ck][row].
// ------------------------------------------------------------------
__global__ __launch_bounds__(256)
void conv_z(const float* __restrict__ z, unsigned short* __restrict__ zh,
            unsigned short* __restrict__ zl, float* __restrict__ snp)
{
    int w = blockIdx.x * 4 + (threadIdx.x >> 6);
    int lane = threadIdx.x & 63;
    int bn = w >> 4, ck = w & 15;            // KC = 512/32 = 16
    int r = bn * 16 + (lane & 15);
    int c = ck * 32 + (lane >> 4) * 8;
    const float4* p = (const float4*)&z[(size_t)r * D_DIM + c];
    float4 v0 = p[0], v1 = p[1];
    float f[8] = {v0.x, v0.y, v0.z, v0.w, v1.x, v1.y, v1.z, v1.w};
    u16x8 hv, lv;
    float s = 0.f;
    #pragma unroll
    for (int j = 0; j < 8; ++j) {
        unsigned short h = f2bf(f[j]);
        hv[j] = h;
        lv[j] = f2bf(f[j] - bf2f(h));
        s = fmaf(f[j], f[j], s);
    }
    size_t o = (size_t)w * 512 + lane * 8;
    *(u16x8*)&zh[o] = hv;
    *(u16x8*)&zl[o] = lv;
    s += __shfl_xor(s, 16);
    s += __shfl_xor(s, 32);                   // 4 lanes of same row now equal
    if ((lane >> 4) == 0) snp[(size_t)ck * N_FR + r] = s;
}

// ------------------------------------------------------------------
// Packed bf16 3-pass split MFMA GEMM — now DOUBLE-BUFFERED (same
// proven dbuf loop shape as argmin_mfma): stage(t+1) issued before
// compute(t), one barrier per step.
// 128x128 tile, 4 waves (2x2), wave 64x64 (4x4 frags of 16x16x32).
// EPI==0: bias+BN epilogue (encoder). EPI==1: bias only (dec codebook).
// ------------------------------------------------------------------
template<int EPI>
__global__ __launch_bounds__(256, 2)
void gemm_pack(const unsigned short* __restrict__ ah_, const unsigned short* __restrict__ al_,
               const unsigned short* __restrict__ bh_, const unsigned short* __restrict__ bl_,
               const float* __restrict__ bias, const float* __restrict__ gamma,
               const float* __restrict__ beta, const float* __restrict__ mean,
               const float* __restrict__ var, float* __restrict__ C,
               int nbi, int nkb, int NJ)
{
    __shared__ unsigned short lds[32768];   // 64KB = 2 x 32KB buffers
    const int tid = threadIdx.x, wid = tid >> 6, lane = tid & 63;
    const int wr = wid >> 1, wc = wid & 1;
    const int bi = blockIdx.x % nbi, bj = blockIdx.x / nbi;

    auto stage = [&](int ks, int bufsel) {
        unsigned short* dst = lds + bufsel * 16384;
        #pragma unroll
        for (int q = 0; q < 8; ++q) {
            int id = wid * 8 + q;
            int arr = id >> 3, rb = id & 7;
            const unsigned short* base = arr == 0 ? ah_ : arr == 1 ? al_ : arr == 2 ? bh_ : bl_;
            size_t b = (size_t)((arr < 2 ? bi : bj) * 8 + rb) * nkb + ks;
            gl_lds16(base + b * 512 + lane * 8, dst + id * 512);
        }
    };

    f32x4 acc[4][4];
    #pragma unroll
    for (int i = 0; i < 4; ++i)
        #pragma unroll
        for (int j = 0; j < 4; ++j) acc[i][j] = (f32x4){0.f, 0.f, 0.f, 0.f};

    stage(0, 0);
    __syncthreads();

    for (int ks = 0; ks < nkb; ++ks) {
        int cur = ks & 1;
        if (ks + 1 < nkb) stage(ks + 1, cur ^ 1);   // prefetch next slice
        const unsigned short* L = lds + cur * 16384;
        bf16x8 ah[4], al[4], bh[4], bl[4];
        #pragma unroll
        for (int i = 0; i < 4; ++i) {
            ah[i] = *(const bf16x8*)(L + (4 * wr + i) * 512 + lane * 8);
            al[i] = *(const bf16x8*)(L + 4096 + (4 * wr + i) * 512 + lane * 8);
        }
        #pragma unroll
        for (int j = 0; j < 4; ++j) {
            bh[j] = *(const bf16x8*)(L + 8192  + (4 * wc + j) * 512 + lane * 8);
            bl[j] = *(const bf16x8*)(L + 12288 + (4 * wc + j) * 512 + lane * 8);
        }
        #pragma unroll
        for (int i = 0; i < 4; ++i)
            #pragma unroll
            for (int j = 0; j < 4; ++j) {
                acc[i][j] = __builtin_amdgcn_mfma_f32_16x16x32_bf16(ah[i], bh[j], acc[i][j], 0, 0, 0);
                acc[i][j] = __builtin_amdgcn_mfma_f32_16x16x32_bf16(ah[i], bl[j], acc[i][j], 0, 0, 0);
                acc[i][j] = __builtin_amdgcn_mfma_f32_16x16x32_bf16(al[i], bh[j], acc[i][j], 0, 0, 0);
            }
        __syncthreads();   // drains prefetch (vmcnt0) + lds reads
    }
    #pragma unroll
    for (int j = 0; j < 4; ++j) {
        int col = bj * 128 + wc * 64 + j * 16 + (lane & 15);
        float bvv = bias[col];
        float g = 0.f, bt = 0.f, mn = 0.f, rs = 0.f;
        if (EPI == 0) {
            g  = gamma[col];
            bt = beta[col];
            mn = mean[col];
            rs = (float)(1.0 / sqrt((double)var[col] + 1e-5));
        }
        #pragma unroll
        for (int i = 0; i < 4; ++i)
            #pragma unroll
            for (int r = 0; r < 4; ++r) {
                int row = bi * 128 + wr * 64 + i * 16 + (lane >> 4) * 4 + r;
                float v = acc[i][j][r] + bvv;
                if (EPI == 0) v = (v - mn) * rs * g + bt;
                C[(size_t)row * NJ + col] = v;
            }
    }
}

// ------------------------------------------------------------------
// Fused distance + argmin (round-6 structure, unchanged from round 10).
// ------------------------------------------------------------------
__global__ __launch_bounds__(256, 2)
void argmin_mfma(const unsigned short* __restrict__ zh, const unsigned short* __restrict__ zl,
                 const unsigned short* __restrict__ ch,
                 const float* __restrict__ se,
                 float* __restrict__ pval, int* __restrict__ pidx)
{
    __shared__ unsigned short lds[32768];   // 64KB = 2 x 32KB buffers
    __shared__ float sv[128][2];
    __shared__ int   si[128][2];
    const int tid = threadIdx.x, wid = tid >> 6, lane = tid & 63;
    const int wr = wid >> 1, wc = wid & 1;
    const int row0 = (int)(blockIdx.x & 255) * 128;
    const int grp  = (int)(blockIdx.x >> 8);

    auto stage = [&](int t, int bufsel) {
        int cc = t >> 4, ks = t & 15;
        int code0 = grp * 1024 + cc * 256;
        unsigned short* dst = lds + bufsel * 16384;
        #pragma unroll
        for (int q = 0; q < 8; ++q) {
            int id = wid * 8 + q;
            const unsigned short* src;
            if (id < 16) {
                int a = id >> 3, rb = id & 7;
                src = (a ? zl : zh) + ((size_t)((row0 >> 4) + rb) * 16 + ks) * 512 + lane * 8;
            } else {
                int cb2 = id - 16;
                src = ch + ((size_t)((code0 >> 4) + cb2) * 16 + ks) * 512 + lane * 8;
            }
            gl_lds16(src, dst + id * 512);
        }
    };

    float bv[16];
    int   bi[16];
    #pragma unroll
    for (int s = 0; s < 16; ++s) { bv[s] = FLT_MAX; bi[s] = 0x7fffffff; }

    f32x4 acc[4][8];
    #pragma unroll
    for (int i = 0; i < 4; ++i)
        #pragma unroll
        for (int j = 0; j < 8; ++j) acc[i][j] = (f32x4){0.f, 0.f, 0.f, 0.f};

    stage(0, 0);
    __syncthreads();

    for (int t = 0; t < 64; ++t) {
        int cur = t & 1;
        if (t < 63) stage(t + 1, cur ^ 1);          // prefetch next step
        const unsigned short* L = lds + cur * 16384;
        bf16x8 ah[4], al[4];
        #pragma unroll
        for (int i = 0; i < 4; ++i) {
            ah[i] = *(const bf16x8*)(L + (wr * 4 + i) * 512 + lane * 8);
            al[i] = *(const bf16x8*)(L + 4096 + (wr * 4 + i) * 512 + lane * 8);
        }
        #pragma unroll
        for (int j = 0; j < 8; ++j) {
            bf16x8 bhj = *(const bf16x8*)(L + 8192 + (wc * 8 + j) * 512 + lane * 8);
            #pragma unroll
            for (int i = 0; i < 4; ++i) {
                acc[i][j] = __builtin_amdgcn_mfma_f32_16x16x32_bf16(ah[i], bhj, acc[i][j], 0, 0, 0);
                acc[i][j] = __builtin_amdgcn_mfma_f32_16x16x32_bf16(al[i], bhj, acc[i][j], 0, 0, 0);
            }
        }
        if ((t & 15) == 15) {   // end of a 256-code chunk: fold argmin, reset acc
            int code0 = grp * 1024 + (t >> 4) * 256;
            #pragma unroll
            for (int j = 0; j < 8; ++j) {
                int code = code0 + wc * 128 + j * 16 + (lane & 15);
                float sev = se[code];
                #pragma unroll
                for (int i = 0; i < 4; ++i)
                    #pragma unroll
                    for (int r = 0; r < 4; ++r) {
                        float key = sev - 2.0f * acc[i][j][r];
                        int s = i * 4 + r;
                        if (key < bv[s]) { bv[s] = key; bi[s] = code; }
                        acc[i][j][r] = 0.f;
                    }
            }
        }
        __syncthreads();   // drains this step's prefetch + lds reads
    }

    #pragma unroll
    for (int s = 0; s < 16; ++s) {
        #pragma unroll
        for (int off = 1; off < 16; off <<= 1) {
            float ov = __shfl_xor(bv[s], off);
            int   oi = __shfl_xor(bi[s], off);
            if (ov < bv[s] || (ov == bv[s] && oi < bi[s])) { bv[s] = ov; bi[s] = oi; }
        }
    }
    if ((lane & 15) == 0) {
        #pragma unroll
        for (int i = 0; i < 4; ++i)
            #pragma unroll
            for (int r = 0; r < 4; ++r) {
                int row = wr * 64 + i * 16 + (lane >> 4) * 4 + r;
                sv[row][wc] = bv[i * 4 + r];
                si[row][wc] = bi[i * 4 + r];
            }
    }
    __syncthreads();
    if (tid < 128) {
        float v0 = sv[tid][0], v1 = sv[tid][1];
        int   i0 = si[tid][0], i1 = si[tid][1];
        float bvv = v0; int bii = i0;
        if (v1 < v0 || (v1 == v0 && i1 < i0)) { bvv = v1; bii = i1; }
        pval[(size_t)grp * N_FR + row0 + tid] = bvv;
        pidx[(size_t)grp * N_FR + row0 + tid] = bii;
    }
}

// ------------------------------------------------------------------
// Merge 4 code-group partials -> final index; histogram; block-reduced
// loss partial: rowloss = ||z_n||^2 (16 slices) + bestkey_n.
// ------------------------------------------------------------------
__global__ __launch_bounds__(256)
void merge_k(const float* __restrict__ pval, const int* __restrict__ pidx,
             const float* __restrict__ snp,
             int* __restrict__ fidx, int* __restrict__ counts,
             float* __restrict__ lpart)
{
    __shared__ float ls[4];
    int tid = threadIdx.x;
    int n = blockIdx.x * 256 + tid;
    float best = pval[n];
    int   bi   = pidx[n];
    #pragma unroll
    for (int c = 1; c < 4; ++c) {
        float v = pval[(long long)c * N_FR + n];
        int   i = pidx[(long long)c * N_FR + n];
        if (v < best) { best = v; bi = i; }   // groups ascend in index; tie keeps lower
    }
    fidx[n] = bi;
    atomicAdd(&counts[bi], 1);
    float sn = 0.f;
    #pragma unroll
    for (int c = 0; c < 16; ++c) sn += snp[(long long)c * N_FR + n];
    float rl = sn + best;
    #pragma unroll
    for (int off = 32; off; off >>= 1) rl += __shfl_xor(rl, off);
    if ((tid & 63) == 0) ls[tid >> 6] = rl;
    __syncthreads();
    if (tid == 0) lpart[blockIdx.x] = ls[0] + ls[1] + ls[2] + ls[3];
}

// ------------------------------------------------------------------
// se[k] = sum_d codebook[k][d]^2 ; blocks 0-15 also zero counts[4096].
// ------------------------------------------------------------------
__global__ __launch_bounds__(256)
void rownorm_k(const float* __restrict__ A, float* __restrict__ sn,
               int* __restrict__ counts)
{
    if (blockIdx.x < 16) counts[blockIdx.x * 256 + threadIdx.x] = 0;
    int row  = blockIdx.x * 4 + (threadIdx.x >> 6);
    int lane = threadIdx.x & 63;
    const float4* p = (const float4*)(A + (long long)row * D_DIM + lane * 8);
    float4 a = p[0], b = p[1];
    float s = a.x*a.x + a.y*a.y + a.z*a.z + a.w*a.w
            + b.x*b.x + b.y*b.y + b.z*b.z + b.w*b.w;
    #pragma unroll
    for (int off = 32; off; off >>= 1) s += __shfl_xor(s, off);
    if (lane == 0) sn[row] = s;
}

__global__ __launch_bounds__(256)
void gather_k(const float* __restrict__ DC, const int* __restrict__ fidx,
              float* __restrict__ outp)
{
    int n = blockIdx.x;
    int id = fidx[n];
    float4 v = ((const float4*)(DC + (long long)id * M_DIM))[threadIdx.x];
    ((float4*)(outp + (long long)n * M_DIM))[threadIdx.x] = v;
}

// ------------------------------------------------------------------
// One-pass encodings writer: zeros + one-hot, coalesced nontemporal f32x4.
// ------------------------------------------------------------------
__global__ __launch_bounds__(256)
void enc_write(const int* __restrict__ fidx, float* __restrict__ enc)
{
    int n    = blockIdx.x * 4 + (threadIdx.x >> 6);
    int lane = threadIdx.x & 63;
    int idx  = fidx[n];
    f32x4* row = (f32x4*)(enc + (size_t)n * K_CB);
    #pragma unroll
    for (int c = 0; c < 16; ++c) {
        int p = c * 64 + lane;
        int b4 = p * 4;
        f32x4 v;
        v.x = (idx == b4 + 0) ? 1.0f : 0.0f;
        v.y = (idx == b4 + 1) ? 1.0f : 0.0f;
        v.z = (idx == b4 + 2) ? 1.0f : 0.0f;
        v.w = (idx == b4 + 3) ? 1.0f : 0.0f;
        __builtin_nontemporal_store(v, &row[p]);
    }
}

__global__ __launch_bounds__(256)
void fin_k(const int* __restrict__ counts, const float* __restrict__ lpart,
           float* __restrict__ scal)
{
    __shared__ double sh[4], lh[4];
    int tid = threadIdx.x;
    double s = 0.0;
    for (int k = tid; k < K_CB; k += 256) {
        double p = (double)counts[k] / (double)N_FR;
        s += p * log(p + 1e-10);
    }
    double l = (tid < 128) ? (double)lpart[tid] : 0.0;
    #pragma unroll
    for (int off = 32; off; off >>= 1) {
        s += __shfl_xor(s, off);
        l += __shfl_xor(l, off);
    }
    if ((tid & 63) == 0) { sh[tid >> 6] = s; lh[tid >> 6] = l; }
    __syncthreads();
    if (tid == 0) {
        double tot = sh[0] + sh[1] + sh[2] + sh[3];
        double L   = lh[0] + lh[1] + lh[2] + lh[3];
        scal[0] = (float)(0.25 * L / ((double)N_FR * (double)D_DIM));
        scal[1] = (float)exp(-tot);
    }
}

extern "C" void kernel_launch(void* const* d_in, const int* in_sizes, int n_in,
                              void* d_out, int out_size, void* d_ws, size_t ws_size,
                              hipStream_t stream)
{
    (void)in_sizes; (void)n_in; (void)out_size; (void)ws_size;
    const float* x        = (const float*)d_in[0];
    const float* enc_w    = (const float*)d_in[1];
    const float* enc_b    = (const float*)d_in[2];
    const float* bn_gamma = (const float*)d_in[3];
    const float* bn_beta  = (const float*)d_in[4];
    const float* bn_mean  = (const float*)d_in[5];
    const float* bn_var   = (const float*)d_in[6];
    const float* cb       = (const float*)d_in[7];
    const float* dec_w    = (const float*)d_in[8];
    const float* dec_b    = (const float*)d_in[9];

    float* outp = (float*)d_out;
    float* z    = outp + Z_OFF;
    float* dc   = outp + DC_OFF;
    unsigned short* xh  = (unsigned short*)(outp + XH_OFF);
    unsigned short* xl  = (unsigned short*)(outp + XL_OFF);
    unsigned short* whp = (unsigned short*)(outp + WH_OFF);
    unsigned short* wlp = (unsigned short*)(outp + WL_OFF);
    unsigned short* chp = (unsigned short*)(outp + CH_OFF);
    unsigned short* clp = (unsigned short*)(outp + CL_OFF);
    unsigned short* zhp = (unsigned short*)(outp + ZH_OFF);
    unsigned short* zlp = (unsigned short*)(outp + ZL_OFF);
    float* pval = outp + PV_OFF;
    int*   pidx = (int*)(outp + PI_OFF);
    unsigned short* dwh = (unsigned short*)(outp + DWH_OFF);
    unsigned short* dwl = (unsigned short*)(outp + DWL_OFF);
    float* snp   = outp + SNP_OFF;
    float* lpart = outp + LP_OFF;

    char*   wsb    = (char*)d_ws;
    int*    fidx   = (int*)wsb;                    // N ints
    int*    counts = (int*)(wsb + 131072);         // K ints
    float*  se     = (float*)(wsb + 147456);       // K floats

    // all four input conversions in one dispatch
    conv_all<<<dim3(17920), 256, 0, stream>>>(x, enc_w, cb, dec_w,
        xh, xl, whp, wlp, chp, clp, dwh, dwl);
    // cb row norms + counts zeroing (replaces memset dispatch)
    rownorm_k<<<dim3(K_CB / 4), 256, 0, stream>>>(cb, se, counts);

    // encoder (MFMA, 3-pass bf16, dbuf) -> z fp32
    gemm_pack<0><<<dim3(1024), 256, 0, stream>>>(xh, xl, whp, wlp,
        enc_b, bn_gamma, bn_beta, bn_mean, bn_var, z, 256, 32, D_DIM);
    // z -> packed zh/zl + row-norm partials (single pass over z)
    conv_z<<<dim3(8192), 256, 0, stream>>>(z, zhp, zlp, snp);

    // decoded codebook (MFMA, dbuf): dec_cb = codebook @ dec_w.T + dec_b
    gemm_pack<1><<<dim3(256), 256, 0, stream>>>(chp, clp, dwh, dwl,
        dec_b, nullptr, nullptr, nullptr, nullptr, dc, 32, 16, M_DIM);

    // fused distances + argmin (2-pass, dbuf, grp-outer XCD-friendly decode)
    argmin_mfma<<<dim3(1024), 256, 0, stream>>>(zhp, zlp, chp, se, pval, pidx);
    merge_k<<<dim3(N_FR / 256), 256, 0, stream>>>(pval, pidx, snp, fidx, counts, lpart);

    gather_k<<<dim3(N_FR), 256, 0, stream>>>(dc, fidx, outp);
    fin_k<<<dim3(1), 256, 0, stream>>>(counts, lpart, outp + LOSS_OFF);

    // final one-pass encodings write (wipes all scratch in that region)
    enc_write<<<dim3(N_FR / 4), 256, 0, stream>>>(fidx, outp + ENC_OFF);
}